// Round 5
// baseline (120.390 us; speedup 1.0000x reference)
//
#include <hip/hip_runtime.h>

#define BATCH 16
#define HH 512
#define WW 512
#define PLANE (HH*WW)

// Compiler memory-order fences for wave-synchronous LDS exchange.
// HW processes a wave's DS ops in order; these stop the compiler from
// reordering ds_write/ds_read across the cross-lane dependency.
#define LDS_WAIT()   asm volatile("s_waitcnt lgkmcnt(0)" ::: "memory")
#define WAVE_FENCE() asm volatile("" ::: "memory")

// ---------------- K1: guide (channel mean) + 15x15 replicate min-pool ----------------
#define T1 64
#define HALO 7
#define LW (T1 + 2*HALO)   // 78

__global__ __launch_bounds__(256) void k1_guide_minpool(
    const float* __restrict__ smoky, float* __restrict__ guide, float* __restrict__ p)
{
    __shared__ float dcp[LW*LW];     // per-pixel channel min, with replicate halo
    __shared__ float vmn[T1*LW];     // vertical 15-min
    int nwg = gridDim.x;             // 1024, divisible by 8
    int wg = (blockIdx.x & 7) * (nwg >> 3) + (blockIdx.x >> 3);  // XCD-chunked swizzle
    int img  = wg >> 6;              // 64 tiles per image
    int tile = wg & 63;
    int y0 = (tile >> 3) * T1;
    int x0 = (tile & 7) * T1;
    int t = threadIdx.x;
    const float* s0 = smoky + (size_t)img * 3 * PLANE;
    float* gpl = guide + (size_t)img * PLANE;
    float* ppl = p     + (size_t)img * PLANE;

    for (int i = t; i < LW*LW; i += 256) {
        int ly = i / LW, lx = i - ly * LW;
        int iy = y0 - HALO + ly, ix = x0 - HALO + lx;
        int cy = min(max(iy, 0), HH-1);
        int cx = min(max(ix, 0), WW-1);
        const float* bp = s0 + cy * WW + cx;
        float c0 = bp[0], c1 = bp[PLANE], c2 = bp[2*PLANE];
        dcp[i] = fminf(fminf(c0, c1), c2);
        if (ly >= HALO && ly < HALO+T1 && lx >= HALO && lx < HALO+T1)
            gpl[iy * WW + ix] = (c0 + c1 + c2) * (1.0f/3.0f);
    }
    __syncthreads();
    for (int i = t; i < T1*LW; i += 256) {
        int r = i / LW, c = i - r * LW;
        float m = dcp[r*LW + c];
        #pragma unroll
        for (int d = 1; d < 15; ++d) m = fminf(m, dcp[(r+d)*LW + c]);
        vmn[i] = m;
    }
    __syncthreads();
    for (int i = t; i < T1*T1; i += 256) {
        int r = i >> 6, c = i & 63;
        float m = vmn[r*LW + c];
        #pragma unroll
        for (int d = 1; d < 15; ++d) m = fminf(m, vmn[r*LW + c + d]);
        ppl[(y0+r)*WW + x0 + c] = m;
    }
}

// ---------------- K2: wave-autonomous fused box sums (I, I^2, p, I*p) -> interleaved (a,b) ----------------
#define RS2 8

__global__ __launch_bounds__(256, 8) void k2_ab(
    const float* __restrict__ guide, const float* __restrict__ p,
    float2* __restrict__ abO)
{
    __shared__ float ls[4][4][80];   // [wave][quantity][slot]
    int nwg = gridDim.x;             // 2048
    int wg = (blockIdx.x & 7) * (nwg >> 3) + (blockIdx.x >> 3);
    int w = threadIdx.x >> 6, l = threadIdx.x & 63;
    int gw = wg * 4 + w;             // 0..8191
    int img   = gw >> 9;             // 512 waves per image
    int cg    = (gw >> 6) & 7;
    int strip = gw & 63;             // 64 row-strips of 8
    int y0 = strip * RS2;
    int c0 = cg * 64;
    const float* gP = guide + (size_t)img * PLANE;
    const float* pP = p     + (size_t)img * PLANE;
    float2* abP = abO + (size_t)img * PLANE;

    // LDS slot s <-> global column c0-7+s
    int col0 = c0 - 7 + l;      // slot l
    int col1 = c0 + 57 + l;     // slot 64+l (lanes 0..13)
    bool v0 = (col0 >= 0);
    bool v1 = (l < 14) && (col1 < WW);

    float sI0=0,sII0=0,sP0=0,sIp0=0;
    float sI1=0,sII1=0,sP1=0,sIp1=0;

    auto loadrow = [&](int y, float& I0, float& Q0, float& I1, float& Q1) {
        I0 = 0.f; Q0 = 0.f; I1 = 0.f; Q1 = 0.f;
        if ((unsigned)y < (unsigned)HH) {
            const float* gr = gP + (size_t)y * WW;
            const float* pr = pP + (size_t)y * WW;
            if (v0) { I0 = gr[col0]; Q0 = pr[col0]; }
            if (v1) { I1 = gr[col1]; Q1 = pr[col1]; }
        }
    };

    // warm-up: window(y0-1) = rows y0-8 .. y0+6 (15 rows, zero outside)
    for (int r = y0 - 8; r <= y0 + 6; ++r) {
        float I0,Q0,I1,Q1; loadrow(r, I0,Q0,I1,Q1);
        sI0+=I0; sII0+=I0*I0; sP0+=Q0; sIp0+=I0*Q0;
        sI1+=I1; sII1+=I1*I1; sP1+=Q1; sIp1+=I1*Q1;
    }
    float aI0,aQ0,aI1,aQ1, bI0,bQ0,bI1,bQ1;
    loadrow(y0 + 7, aI0,aQ0,aI1,aQ1);   // to add at iter y0
    loadrow(y0 - 8, bI0,bQ0,bI1,bQ1);   // to subtract at iter y0

    float* L = &ls[w][0][0];
    const float inv225 = 1.0f/225.0f;
    for (int y = y0; y < y0 + RS2; ++y) {
        // window(y) = window(y-1) + row(y+7) - row(y-8)
        sI0 += aI0 - bI0;  sII0 += aI0*aI0 - bI0*bI0;
        sP0 += aQ0 - bQ0;  sIp0 += aI0*aQ0 - bI0*bQ0;
        sI1 += aI1 - bI1;  sII1 += aI1*aI1 - bI1*bI1;
        sP1 += aQ1 - bQ1;  sIp1 += aI1*aQ1 - bI1*bQ1;
        // prefetch next iteration's rows (in flight during LDS phase)
        loadrow(y + 8, aI0,aQ0,aI1,aQ1);
        loadrow(y - 7, bI0,bQ0,bI1,bQ1);
        // wave-private LDS exchange (fenced wave-synchronous pattern)
        L[l] = sI0; L[80+l] = sII0; L[160+l] = sP0; L[240+l] = sIp0;
        if (l < 14) { L[64+l] = sI1; L[144+l] = sII1; L[224+l] = sP1; L[304+l] = sIp1; }
        LDS_WAIT();
        float SI=0,SII=0,SP=0,SIp=0;
        #pragma unroll
        for (int d = 0; d < 15; ++d) {
            SI  += L[l+d];
            SII += L[80+l+d];
            SP  += L[160+l+d];
            SIp += L[240+l+d];
        }
        WAVE_FENCE();   // keep next iter's ds_writes below this iter's ds_reads
        float mI = SI*inv225, mP = SP*inv225;
        float va = (SIp*inv225 - mI*mP) / (SII*inv225 - mI*mI + 1e-3f);
        abP[(size_t)y*WW + c0 + l] = make_float2(va, mP - va*mI);
    }
}

// ---------------- K3: wave-autonomous box sums of (a,b) + guided output + combine ----------------
__global__ __launch_bounds__(256, 8) void k3_final(
    const float2* __restrict__ abI, const float* __restrict__ guide,
    const float* __restrict__ smoky, const float* __restrict__ rho,
    float* __restrict__ out)
{
    __shared__ float ls[4][2][80];
    int nwg = gridDim.x;             // 2048
    int wg = (blockIdx.x & 7) * (nwg >> 3) + (blockIdx.x >> 3);
    int w = threadIdx.x >> 6, l = threadIdx.x & 63;
    int gw = wg * 4 + w;
    int img   = gw >> 9;
    int cg    = (gw >> 6) & 7;
    int strip = gw & 63;
    int y0 = strip * RS2;
    int c0 = cg * 64;
    const float2* abP = abI + (size_t)img * PLANE;
    const float* gP = guide + (size_t)img * PLANE;
    const float* sP = smoky + (size_t)img * 3 * PLANE;
    const float* rP = rho   + (size_t)img * 3 * PLANE;
    float* oP = out + (size_t)img * 3 * PLANE;

    int col0 = c0 - 7 + l;
    int col1 = c0 + 57 + l;
    bool v0 = (col0 >= 0);
    bool v1 = (l < 14) && (col1 < WW);

    float sa0=0, sb0=0, sa1=0, sb1=0;

    auto loadrow = [&](int y, float2& P0, float2& P1) {
        P0 = make_float2(0.f, 0.f); P1 = make_float2(0.f, 0.f);
        if ((unsigned)y < (unsigned)HH) {
            const float2* r = abP + (size_t)y * WW;
            if (v0) P0 = r[col0];
            if (v1) P1 = r[col1];
        }
    };

    for (int r = y0 - 8; r <= y0 + 6; ++r) {
        float2 P0, P1; loadrow(r, P0, P1);
        sa0 += P0.x; sb0 += P0.y; sa1 += P1.x; sb1 += P1.y;
    }
    float2 addA0, addA1, subA0, subA1;
    loadrow(y0 + 7, addA0, addA1);
    loadrow(y0 - 8, subA0, subA1);

    // prefetched emit operands (guide/smoky/rho at current row)
    float eg, es0,es1,es2, er0,er1,er2;
    int yend = y0 + RS2;
    auto loademit = [&](int y) {
        if (y < yend) {
            size_t off = (size_t)y*WW + c0 + l;
            eg  = gP[off];
            es0 = sP[off]; es1 = sP[off+PLANE]; es2 = sP[off+2*PLANE];
            er0 = rP[off]; er1 = rP[off+PLANE]; er2 = rP[off+2*PLANE];
        }
    };
    loademit(y0);

    float* L = &ls[w][0][0];
    const float inv225 = 1.0f/225.0f;
    const float inv11  = 1.0f/1.1f;
    for (int y = y0; y < yend; ++y) {
        sa0 += addA0.x - subA0.x;  sb0 += addA0.y - subA0.y;
        sa1 += addA1.x - subA1.x;  sb1 += addA1.y - subA1.y;
        // consume current emit operands into locals
        float g = eg, s0 = es0, s1 = es1, s2 = es2, r0 = er0, r1 = er1, r2 = er2;
        // prefetch next iteration
        loadrow(y + 8, addA0, addA1);
        loadrow(y - 7, subA0, subA1);
        loademit(y + 1);
        // wave-private LDS exchange (fenced wave-synchronous pattern)
        L[l] = sa0; L[80+l] = sb0;
        if (l < 14) { L[64+l] = sa1; L[144+l] = sb1; }
        LDS_WAIT();
        float SA=0, SB=0;
        #pragma unroll
        for (int d = 0; d < 15; ++d) { SA += L[l+d]; SB += L[80+l+d]; }
        WAVE_FENCE();
        float dcr = SA*inv225*g + SB*inv225;
        float f = (0.1f + dcr) * inv11;
        size_t off = (size_t)y*WW + c0 + l;
        oP[off]          = s0 - f*(1.0f - r0);
        oP[off+PLANE]    = s1 - f*(1.0f - r1);
        oP[off+2*PLANE]  = s2 - f*(1.0f - r2);
    }
}

extern "C" void kernel_launch(void* const* d_in, const int* in_sizes, int n_in,
                              void* d_out, int out_size, void* d_ws, size_t ws_size,
                              hipStream_t stream) {
    const float* smoky = (const float*)d_in[0];
    const float* rho   = (const float*)d_in[1];
    float* out = (float*)d_out;
    float* ws  = (float*)d_ws;
    const size_t P = (size_t)BATCH * PLANE;
    float* guide = ws;
    float* p     = ws + P;
    float2* ab   = (float2*)(ws + 2*P);   // interleaved (a,b): 2P floats

    k1_guide_minpool<<<BATCH*64, 256, 0, stream>>>(smoky, guide, p);
    k2_ab<<<BATCH*128, 256, 0, stream>>>(guide, p, ab);
    k3_final<<<BATCH*128, 256, 0, stream>>>(ab, guide, smoky, rho, out);
}